// Round 1
// 132.364 us; speedup vs baseline: 1.0135x; 1.0135x over previous
//
#include <hip/hip_runtime.h>

#define B_DIM 4096
#define I_DIM 1024
#define O_DIM 1024
#define ON_DIM 4096      // O * N fan-in columns
#define TILE_HALFS 4096  // one 128(m) x 32(k) fp16 tile image = 8 KB
                         // image order: [kb8(4)][m(128)][j(8)] halfs

typedef _Float16 half8  __attribute__((ext_vector_type(8)));
typedef _Float16 half4_t __attribute__((ext_vector_type(4)));
typedef float    floatx4 __attribute__((ext_vector_type(4)));

// ---------------------------------------------------------------------------
// Kernel A: per-row softmax stats (max, 1/sum) — one wave per row.
// ---------------------------------------------------------------------------
__global__ __launch_bounds__(256)
void ltn_stats(const float* __restrict__ logits, float2* __restrict__ stats) {
  const int t = threadIdx.x, lane = t & 63, wv = t >> 6;
  const int row = blockIdx.x * 4 + wv;
  const float4* src = (const float4*)(logits + (size_t)row * I_DIM);
  float4 v[4];
#pragma unroll
  for (int j = 0; j < 4; j++) v[j] = src[j * 64 + lane];
  float m = -1e30f;
#pragma unroll
  for (int j = 0; j < 4; j++)
    m = fmaxf(m, fmaxf(fmaxf(v[j].x, v[j].y), fmaxf(v[j].z, v[j].w)));
#pragma unroll
  for (int off = 1; off < 64; off <<= 1) m = fmaxf(m, __shfl_xor(m, off));
  float s = 0.0f;
#pragma unroll
  for (int j = 0; j < 4; j++) {
    s += __expf(v[j].x - m) + __expf(v[j].y - m)
       + __expf(v[j].z - m) + __expf(v[j].w - m);
  }
#pragma unroll
  for (int off = 1; off < 64; off <<= 1) s += __shfl_xor(s, off);
  if (lane == 0) stats[row] = make_float2(m, 1.0f / s);
}

// ---------------------------------------------------------------------------
// Kernel B: fully-coalesced tile writer.
//  blocks [0,1024):    wt tile (nb,kb): softmax-normalize 128x32 logits block
//  blocks [1024,2048): xt tile (mb,kt): fp32->fp16 convert 128x32 x block
// ---------------------------------------------------------------------------
__global__ __launch_bounds__(256)
void ltn_tile(const float* __restrict__ logits, const float* __restrict__ x,
              const float2* __restrict__ stats,
              _Float16* __restrict__ wt, _Float16* __restrict__ xt) {
  const int t  = threadIdx.x;
  const int nn = t >> 1;        // row within 128-tile
  const int hf = t & 1;         // which 16-k half of the 32-k tile
  if (blockIdx.x < 1024) {
    const int nb = blockIdx.x >> 5, kb = blockIdx.x & 31;
    const int row = nb * 128 + nn;
    const float2 st = stats[row];
    const float4* src = (const float4*)(logits + (size_t)row * I_DIM + kb * 32 + hf * 16);
    const float4 a = src[0], b = src[1], c = src[2], d = src[3];
    half8 h0, h1;
    h0[0] = (_Float16)(__expf(a.x - st.x) * st.y);
    h0[1] = (_Float16)(__expf(a.y - st.x) * st.y);
    h0[2] = (_Float16)(__expf(a.z - st.x) * st.y);
    h0[3] = (_Float16)(__expf(a.w - st.x) * st.y);
    h0[4] = (_Float16)(__expf(b.x - st.x) * st.y);
    h0[5] = (_Float16)(__expf(b.y - st.x) * st.y);
    h0[6] = (_Float16)(__expf(b.z - st.x) * st.y);
    h0[7] = (_Float16)(__expf(b.w - st.x) * st.y);
    h1[0] = (_Float16)(__expf(c.x - st.x) * st.y);
    h1[1] = (_Float16)(__expf(c.y - st.x) * st.y);
    h1[2] = (_Float16)(__expf(c.z - st.x) * st.y);
    h1[3] = (_Float16)(__expf(c.w - st.x) * st.y);
    h1[4] = (_Float16)(__expf(d.x - st.x) * st.y);
    h1[5] = (_Float16)(__expf(d.y - st.x) * st.y);
    h1[6] = (_Float16)(__expf(d.z - st.x) * st.y);
    h1[7] = (_Float16)(__expf(d.w - st.x) * st.y);
    _Float16* base = wt + ((size_t)nb * 32 + kb) * TILE_HALFS + (hf * 2) * 1024 + nn * 8;
    *(half8*)base = h0;
    *(half8*)(base + 1024) = h1;
  } else {
    const int bid = blockIdx.x - 1024;
    const int mb = bid >> 5, kt = bid & 31;
    const int row = mb * 128 + nn;
    const float4* src = (const float4*)(x + (size_t)row * I_DIM + kt * 32 + hf * 16);
    const float4 a = src[0], b = src[1], c = src[2], d = src[3];
    half8 h0, h1;
    h0[0] = (_Float16)a.x; h0[1] = (_Float16)a.y; h0[2] = (_Float16)a.z; h0[3] = (_Float16)a.w;
    h0[4] = (_Float16)b.x; h0[5] = (_Float16)b.y; h0[6] = (_Float16)b.z; h0[7] = (_Float16)b.w;
    h1[0] = (_Float16)c.x; h1[1] = (_Float16)c.y; h1[2] = (_Float16)c.z; h1[3] = (_Float16)c.w;
    h1[4] = (_Float16)d.x; h1[5] = (_Float16)d.y; h1[6] = (_Float16)d.z; h1[7] = (_Float16)d.w;
    _Float16* base = xt + ((size_t)mb * 32 + kt) * TILE_HALFS + (hf * 2) * 1024 + nn * 8;
    *(half8*)base = h0;
    *(half8*)(base + 1024) = h1;
  }
}

// ---------------------------------------------------------------------------
// GEMM + sigmoid + 16-corner LUT. 256x256 block tile (8 waves, 4x2), BK=32.
// R8 restructure: TRIPLE-buffered LDS (3 x 32KB) with a 2-deep counted-vmcnt
// pipeline (T3/T4). The old loop used __syncthreads() per K-step, whose
// vmcnt(0)+lgkmcnt(0) drained the whole staging queue every iteration — the
// measured 610 TF matches the known ~600-680 TF ceiling of that structure.
// New loop per K-step kt:
//   s_waitcnt vmcnt(4)   // stage(kt) landed; stage(kt+1)'s 4 stay IN FLIGHT
//   s_barrier            // all waves' kt-data landed; all kt-1 reads consumed
//   stage(kt+2) -> buffer that held kt-1 (safe: reads completed pre-barrier,
//                  since every ds_read fragment is consumed by an MFMA)
//   compute(kt) with s_setprio(1) around the MFMA cluster (T5)
// Steady state: 8 GLLs outstanding per wave, never drained to 0 in the loop.
// Grid flattened to 256 with XCD-chunked swizzle (T1): each XCD owns a
// 4(mb) x 8(nb) chunk -> 6 MB panel working set per 4 MB L2 (was 9 MB).
// ---------------------------------------------------------------------------
__global__ __launch_bounds__(512, 2)
void ltn_gemm_lut(const _Float16* __restrict__ xt,   // tiles [32*32][TILE_HALFS]
                  const _Float16* __restrict__ wt,
                  const float* __restrict__ lut,     // [O][16]
                  float* __restrict__ out) {         // [B][O]
  // 3 buffers x (A: 8192 halfs | B: 8192 halfs) = 96 KB
  __shared__ _Float16 sm[3 * 16384];

  const int tid  = threadIdx.x;
  const int lane = tid & 63;
  const int wv   = tid >> 6;     // 0..7
  const int wr   = wv >> 1;      // row-wave 0..3  (64 rows each)
  const int wc   = wv & 1;       // col-wave 0..1  (128 cols each)

  // XCD-chunked swizzle: id&7 -> XCD (round-robin dispatch); XCD k owns a
  // contiguous 4x8 chunk of the 16x16 (mb,nb) grid. Bijective.
  const int id  = blockIdx.x;    // 0..255
  const int xcd = id & 7;
  const int li  = id >> 3;       // 0..31
  const int mb  = (xcd & 3) * 4 + (li & 3);
  const int nb  = (xcd >> 2) * 8 + (li >> 2);

  const int fm = lane & 15;
  const int kq = lane >> 4;

  const size_t baseA = (size_t)(mb * 2) * 32 * TILE_HALFS;
  const size_t baseB = (size_t)(nb * 2) * 32 * TILE_HALFS;

  floatx4 acc[4][8];
#pragma unroll
  for (int i = 0; i < 4; i++)
#pragma unroll
    for (int j = 0; j < 8; j++) acc[i][j] = (floatx4)0.0f;

  // 32 chunks of 1KB per buffer (16 A + 16 B); 4 GLLs per wave per stage.
  auto stage = [&](int bufOff /*halfs*/, int kt) {
#pragma unroll
    for (int s = 0; s < 4; s++) {
      const int c   = wv * 4 + s;        // 0..31, wave-uniform split
      const int cc  = c & 15;            // chunk within matrix
      const int tl  = cc >> 3;           // which 128-row tile (0/1)
      const int sub = cc & 7;            // 1KB sub-chunk
      const _Float16* g;
      int dst;
      if (c < 16) {
        g = xt + baseA + (size_t)(tl * 32 + kt) * TILE_HALFS + sub * 512 + lane * 8;
        dst = bufOff + cc * 512;
      } else {
        g = wt + baseB + (size_t)(tl * 32 + kt) * TILE_HALFS + sub * 512 + lane * 8;
        dst = bufOff + 8192 + cc * 512;
      }
      __builtin_amdgcn_global_load_lds(
          (const __attribute__((address_space(1))) void*)g,
          (__attribute__((address_space(3))) void*)(sm + dst), 16, 0, 0);
    }
  };

  auto compute = [&](int bufOff) {
    half8 af[4], bf[8];
#pragma unroll
    for (int f = 0; f < 4; f++)
      af[f] = *(const half8*)&sm[bufOff + ((wr >> 1) * 4 + kq) * 1024
                                 + ((wr & 1) * 64 + f * 16 + fm) * 8];
#pragma unroll
    for (int g = 0; g < 8; g++)
      bf[g] = *(const half8*)&sm[bufOff + 8192 + (wc * 4 + kq) * 1024
                                 + (g * 16 + fm) * 8];
    __builtin_amdgcn_s_setprio(1);
#pragma unroll
    for (int mt = 0; mt < 4; mt++)
#pragma unroll
      for (int nt = 0; nt < 8; nt++)
        acc[mt][nt] = __builtin_amdgcn_mfma_f32_16x16x32_f16(
            af[mt], bf[nt], acc[mt][nt], 0, 0, 0);
    __builtin_amdgcn_s_setprio(0);
  };

  // Prologue: fill pipeline 2 deep (8 GLLs outstanding per wave).
  stage(0, 0);
  stage(16384, 1);
  int o0 = 0, o1 = 16384, o2 = 32768;   // read buf, in-flight buf, free buf

  for (int kt = 0; kt < 32; kt++) {
    // Wait (before the barrier!) for this wave's stage(kt) loads only;
    // stage(kt+1) stays in flight across the barrier (T4 counted vmcnt).
    if (kt < 31) asm volatile("s_waitcnt vmcnt(4)" ::: "memory");
    else         asm volatile("s_waitcnt vmcnt(0)" ::: "memory");
    __builtin_amdgcn_s_barrier();
    __builtin_amdgcn_sched_barrier(0);
    if (kt + 2 < 32) stage(o2, kt + 2);  // o2 held kt-1: reads done pre-barrier
    compute(o0);
    const int t0 = o0; o0 = o1; o1 = o2; o2 = t0;
  }

  // ---- fused epilogue: sigmoid -> gather 4 fan-in values -> LUT contraction
  // C/D layout: col = lane&15, row = (lane>>4)*4 + reg. The 4 n-values of one
  // o live in 4 consecutive lanes.
#pragma unroll
  for (int nt = 0; nt < 8; nt++) {
    const int o = (nb * 256 + wc * 128 + nt * 16 + fm) >> 2;
    const float4* lt4 = (const float4*)(lut + (size_t)o * 16);
    const float4 L0 = lt4[0], L1 = lt4[1], L2 = lt4[2], L3 = lt4[3];
#pragma unroll
    for (int mt = 0; mt < 4; mt++) {
#pragma unroll
      for (int r = 0; r < 4; r++) {
        const float v  = acc[mt][nt][r];
        const float sv = 1.0f / (1.0f + __expf(-v));
        const float s1 = __shfl_down(sv, 1);
        const float s2 = __shfl_down(sv, 2);
        const float s3 = __shfl_down(sv, 3);
        if ((lane & 3) == 0) {
          const float s0 = sv;
          const float a0 = L0.x + (L2.x - L0.x) * s3;
          const float a1 = L0.y + (L2.y - L0.y) * s3;
          const float a2 = L0.z + (L2.z - L0.z) * s3;
          const float a3 = L0.w + (L2.w - L0.w) * s3;
          const float a4 = L1.x + (L3.x - L1.x) * s3;
          const float a5 = L1.y + (L3.y - L1.y) * s3;
          const float a6 = L1.z + (L3.z - L1.z) * s3;
          const float a7 = L1.w + (L3.w - L1.w) * s3;
          const float b0 = a0 + (a4 - a0) * s2;
          const float b1 = a1 + (a5 - a1) * s2;
          const float b2 = a2 + (a6 - a2) * s2;
          const float b3 = a3 + (a7 - a3) * s2;
          const float c0 = b0 + (b2 - b0) * s1;
          const float c1 = b1 + (b3 - b1) * s1;
          const float res = c0 + (c1 - c0) * s0;
          const int row = mb * 256 + wr * 64 + mt * 16 + (lane >> 4) * 4 + r;
          out[(size_t)row * O_DIM + o] = res;
        }
      }
    }
  }
}

// ---------------------------------------------------------------------------
extern "C" void kernel_launch(void* const* d_in, const int* in_sizes, int n_in,
                              void* d_out, int out_size, void* d_ws, size_t ws_size,
                              hipStream_t stream) {
  const float* x      = (const float*)d_in[0];  // (B, I)
  const float* logits = (const float*)d_in[1];  // (O, N, I)
  const float* lut    = (const float*)d_in[2];  // (O, 16)
  float* out          = (float*)d_out;          // (B, O)

  _Float16* wt = (_Float16*)d_ws;                                  // 8 MB tiled
  _Float16* xt = (_Float16*)d_ws + (size_t)ON_DIM * I_DIM;         // 8 MB tiled
  // stats scratch parked in d_out (32 KB); GEMM fully overwrites d_out later.
  float2* stats = (float2*)d_out;

  ltn_stats<<<1024, 256, 0, stream>>>(logits, stats);
  ltn_tile<<<2048, 256, 0, stream>>>(logits, x, stats, wt, xt);
  ltn_gemm_lut<<<256, 512, 0, stream>>>(xt, wt, lut, out);
}